// Round 1
// baseline (24025.188 us; speedup 1.0000x reference)
//
#include <hip/hip_runtime.h>
#include <cstdint>
#include <cstddef>

typedef _Float16 f16;
typedef _Float16 f16x8 __attribute__((ext_vector_type(8)));
typedef float f32x4 __attribute__((ext_vector_type(4)));

#define B_  128
#define T_  256
#define U_  1024

// ---- workspace offsets (bytes) ----
#define WS_BAR  0u
#define WS_HHI  4096u
#define WS_HLO  (WS_HHI + 262144u)      // h planes: [128][1024] f16, column-swizzled
#define WS_RH   (WS_HLO + 262144u)      // rh plane: [128][1024] f16, swizzled
#define WS_Z    (WS_RH  + 262144u)      // z: [128][1024] f32
#define WS_WT   (WS_Z   + 524288u)      // recurrent_kernel^T f16 [4096][1024]
#define WS_KDT  (WS_WT  + 8388608u)     // kernel_d^T f16 [4096][128]
#define WS_KST  (WS_KDT + 1048576u)     // kernel_s^T f16 [4096][128]
#define WS_END  (WS_KST + 1048576u)

// ---- LDS offsets (bytes) ----
#define L_STHI 0        // staged h_hi (or rh in phase2): [32][2048B]
#define L_STLO 65536    // staged h_lo
#define L_SCR  131072   // [_d|_s](t): [32 rows][256 f16], swizzled, 16384B
#define L_BASE 147456   // base acc / o-stash: [6 tiles][256] f32
#define L_EXCH 153600   // reduction exchange: [2][3][256] f32
#define L_P2B  159744   // phase2 base: [2][256] f32
#define L_DST  161792   // d-state: [2 parity][32][2] f32
#define L_CHC  162304   // ch(t) cache: [32] int
#define LDS_SZ 162560

#define MFMA16(a,b,c) __builtin_amdgcn_mfma_f32_16x16x32_f16((a),(b),(c),0,0,0)

__device__ __forceinline__ float sigm(float v) { return 1.0f / (1.0f + __expf(-v)); }

// ---------- prep: transpose + f32->f16 convert weights ----------
__global__ __launch_bounds__(256) void prep_kernel(const float* __restrict__ rk,
                                                   const float* __restrict__ kd,
                                                   const float* __restrict__ ks,
                                                   f16* __restrict__ wT,
                                                   f16* __restrict__ kdT,
                                                   f16* __restrict__ ksT) {
  size_t i = (size_t)blockIdx.x * 256 + threadIdx.x;
  if (i < 4194304u) {                     // 1024*4096
    int k = (int)(i >> 12), n = (int)(i & 4095);
    wT[(size_t)n * 1024 + k] = (f16)rk[i];
  } else if (i < 4718592u) {              // + 128*4096
    size_t j = i - 4194304u;
    int k = (int)(j >> 12), n = (int)(j & 4095);
    kdT[(size_t)n * 128 + k] = (f16)kd[j];
  } else {                                // + 128*4096
    size_t j = i - 4718592u;
    int k = (int)(j >> 12), n = (int)(j & 4095);
    ksT[(size_t)n * 128 + k] = (f16)ks[j];
  }
}

// ---------- grid barrier: monotonic counter, split arrive/wait ----------
__device__ __forceinline__ void bar_arrive(unsigned* cnt) {
  __syncthreads();
  if (threadIdx.x == 0) {
    __threadfence();
    __hip_atomic_fetch_add(cnt, 1u, __ATOMIC_RELEASE, __HIP_MEMORY_SCOPE_AGENT);
  }
}
__device__ __forceinline__ void bar_wait(unsigned* cnt, unsigned target) {
  if (threadIdx.x == 0) {
    while (__hip_atomic_load(cnt, __ATOMIC_ACQUIRE, __HIP_MEMORY_SCOPE_AGENT) < target)
      __builtin_amdgcn_s_sleep(2);
    __threadfence();
  }
  __syncthreads();
}

// ---------- _d(t), _s(t) into LDS scratch (waves 2..5), d-state update ----------
__device__ __forceinline__ void compute_ds(int t, const float* __restrict__ x,
                                           const float* __restrict__ Wd, const float* __restrict__ bd,
                                           const float* __restrict__ Ws, const float* __restrict__ bs,
                                           char* lds, int row0, int wid, int lane) {
  const int pOld = (t & 1) ^ 1, pNew = t & 1;
  float* dOld = (float*)(lds + L_DST) + pOld * 64;
  float* dNew = (float*)(lds + L_DST) + pNew * 64;
  if (wid == 2 || wid == 3) {
    const int j = (wid - 2) * 64 + lane;      // 0..127
    const float w0 = Wd[j], w1 = Wd[128 + j], b0 = bd[j];
    for (int r = 0; r < 32; ++r) {
      const size_t xb = ((size_t)(row0 + r) * T_ + t) * 5;
      float d0 = dOld[r * 2 + 0] + x[xb + 0];
      float d1 = dOld[r * 2 + 1] + x[xb + 1];
      if (wid == 2 && lane == r) { dNew[r * 2 + 0] = d0; dNew[r * 2 + 1] = d1; }
      float v = tanhf(d0 * w0 + d1 * w1 + b0);
      *(f16*)(lds + L_SCR + r * 512 + ((2 * j) ^ ((r & 7) << 4))) = (f16)v;
    }
  } else if (wid == 4 || wid == 5) {
    const int j = (wid - 4) * 64 + lane;      // 0..127
    const float w0 = Ws[j], w1 = Ws[128 + j], w2 = Ws[256 + j], b0 = bs[j];
    for (int r = 0; r < 32; ++r) {
      const size_t xb = ((size_t)(row0 + r) * T_ + t) * 5;
      float v = tanhf(x[xb + 2] * w0 + x[xb + 3] * w1 + x[xb + 4] * w2 + b0);
      *(f16*)(lds + L_SCR + r * 512 + ((2 * (128 + j)) ^ ((r & 7) << 4))) = (f16)v;
    }
  }
}

// ---------- persistent SGRU kernel ----------
__global__ __launch_bounds__(512) void sgru_kernel(
    const float* __restrict__ x, const int* __restrict__ ch,
    const float* __restrict__ Wd, const float* __restrict__ bd,
    const float* __restrict__ Ws, const float* __restrict__ bs,
    const float* __restrict__ kernel_c, const float* __restrict__ bias,
    char* __restrict__ wsb, float* __restrict__ out) {
  extern __shared__ char lds[];
  const int tid  = threadIdx.x;
  const int wid  = tid >> 6;
  const int lane = tid & 63;
  const int lcol = lane & 15;
  const int kc   = lane >> 4;
  const int blk  = blockIdx.x;
  const int rg   = blk >> 6;        // row group 0..3
  const int c    = blk & 63;        // col group 0..63
  const int row0 = rg * 32;
  const int rt   = wid & 1;         // row-tile for recurrent MFMA
  const int kq   = wid >> 1;        // k-quarter 0..3

  const f16* __restrict__ wT  = (const f16*)(wsb + WS_WT);
  const f16* __restrict__ kdT = (const f16*)(wsb + WS_KDT);
  const f16* __restrict__ ksT = (const f16*)(wsb + WS_KST);
  unsigned* cntA = (unsigned*)(wsb + WS_BAR);
  unsigned* cntB = (unsigned*)(wsb + WS_BAR + 64);

  // ---- pre-loop: d-state parity-1 = 0, ch(0), _d/_s(0), resident B fragments ----
  if (tid < 64) ((float*)(lds + L_DST))[64 + tid] = 0.0f;
  if (tid < 32) ((int*)(lds + L_CHC))[tid] = ch[(size_t)(row0 + tid) * T_];
  __syncthreads();
  compute_ds(0, x, Wd, bd, Ws, bs, lds, row0, wid, lane);

  f16x8 Bp1[3][8];      // this wave's k-quarter of [Rzr|Ro] for the 3 col-tiles
  #pragma unroll
  for (int ct = 0; ct < 3; ++ct) {
    const int cc = 48 * c + 16 * ct + lcol;            // combined col
    const int orig = cc + (cc >= 2048 ? 1024 : 0);     // o-region -> Ro cols
    const f16* wp = wT + (size_t)orig * 1024;
    #pragma unroll
    for (int j = 0; j < 8; ++j)
      Bp1[ct][j] = *(const f16x8*)(wp + (kq * 8 + j) * 32 + kc * 8);
  }
  __syncthreads();

  for (int t = 0; ; ++t) {
    // ================= PHASE 1 =================
    // S0: stage h planes (rows row0..row0+32), layout already swizzled in global
    {
      const char* sH = wsb + WS_HHI + (size_t)row0 * 2048;
      const char* sL = wsb + WS_HLO + (size_t)row0 * 2048;
      #pragma unroll
      for (int it = 0; it < 8; ++it) {
        const int off = it * 8192 + tid * 16;
        *(f16x8*)(lds + L_STHI + off) = *(const f16x8*)(sH + off);
        *(f16x8*)(lds + L_STLO + off) = *(const f16x8*)(sL + off);
      }
    }
    // S1: base(t) for the 6 P1 tiles (waves 0..5): [_d|_s] @ [kd;ks] + gather + bias
    f32x4 accb = {0.f, 0.f, 0.f, 0.f};
    bool is_o = false;
    if (wid < 6 && t < T_) {
      const int tct = wid >> 1, trt = wid & 1;
      const int ccb = 48 * c + 16 * tct;
      is_o = (ccb >= 2048);
      const int bcol = ccb + (is_o ? 1024 : 0) + lcol;
      const f16* kdp = kdT + (size_t)bcol * 128;
      const f16* ksp = ksT + (size_t)bcol * 128;
      const int arow = 16 * trt + lcol;
      const int asw = (arow & 7) << 4;
      #pragma unroll
      for (int j = 0; j < 8; ++j) {
        f16x8 a = *(f16x8*)(lds + L_SCR + arow * 512 + ((j * 64 + kc * 16) ^ asw));
        f16x8 b = (j < 4) ? *(const f16x8*)(kdp + j * 32 + kc * 8)
                          : *(const f16x8*)(ksp + (j - 4) * 32 + kc * 8);
        accb = MFMA16(a, b, accb);
      }
      #pragma unroll
      for (int e = 0; e < 4; ++e) {
        const int lrow = 16 * trt + kc * 4 + e;
        const int crow = ((int*)(lds + L_CHC))[lrow];
        accb[e] += kernel_c[(size_t)crow * 4096 + bcol] + bias[bcol];
      }
      if (!is_o) {  // zr tiles: park in LDS now; o tiles: stash later (S5)
        float* bsl = (float*)(lds + L_BASE) + wid * 256;
        #pragma unroll
        for (int e = 0; e < 4; ++e) bsl[(kc * 4 + e) * 16 + lcol] = accb[e];
      }
    }
    __syncthreads();   // stage + zr base ready

    // S2: recurrent MFMA: h_t @ [Rzr|Ro], 2-term (hi+lo), k-quarter per wave
    f32x4 acc[3] = {{0,0,0,0},{0,0,0,0},{0,0,0,0}};
    {
      const int lrow = 16 * rt + lcol;
      const int hb = lrow * 2048;
      const int hsw = (lrow & 7) << 4;
      #pragma unroll
      for (int j = 0; j < 8; ++j) {
        const int kb = (((kq * 8 + j) * 64 + kc * 16) ^ hsw);
        f16x8 ahi = *(f16x8*)(lds + L_STHI + hb + kb);
        f16x8 alo = *(f16x8*)(lds + L_STLO + hb + kb);
        #pragma unroll
        for (int q = 0; q < 3; ++q) {
          acc[q] = MFMA16(ahi, Bp1[q][j], acc[q]);
          acc[q] = MFMA16(alo, Bp1[q][j], acc[q]);
        }
      }
    }
    __syncthreads();

    // S3: reduce 4 k-quarters into kq==0 waves (3 serialized rounds)
    {
      float* ex = (float*)(lds + L_EXCH) + rt * 768;
      for (int rr = 1; rr <= 3; ++rr) {
        if (kq == rr) {
          #pragma unroll
          for (int q = 0; q < 3; ++q)
            #pragma unroll
            for (int e = 0; e < 4; ++e)
              ex[q * 256 + (kc * 4 + e) * 16 + lcol] = acc[q][e];
        }
        __syncthreads();
        if (kq == 0) {
          #pragma unroll
          for (int q = 0; q < 3; ++q)
            #pragma unroll
            for (int e = 0; e < 4; ++e)
              acc[q][e] += ex[q * 256 + (kc * 4 + e) * 16 + lcol];
        }
        __syncthreads();
      }
    }

    // S4: epilogue (waves 0,1): z -> zbuf, r -> rh plane, o -> output
    if (wid < 2) {
      #pragma unroll
      for (int q = 0; q < 3; ++q) {
        const int ccb = 48 * c + 16 * q;
        const int cc_n = ccb + lcol;
        const float* bsl = (float*)(lds + L_BASE) + (q * 2 + rt) * 256;
        #pragma unroll
        for (int e = 0; e < 4; ++e) {
          const int m = kc * 4 + e;
          const int lrow = 16 * rt + m;
          const int brow = row0 + lrow;
          if (ccb < 2048) {
            if (t < T_) {
              const float pre = acc[q][e] + bsl[m * 16 + lcol];
              const float sg = sigm(pre);
              if (ccb < 1024) {
                ((float*)(wsb + WS_Z))[(size_t)brow * 1024 + cc_n] = sg;
              } else {
                const int kcol = cc_n - 1024;
                const int lb = lrow * 2048 + ((2 * kcol) ^ ((lrow & 7) << 4));
                const float hv = (float)*(f16*)(lds + L_STHI + lb) +
                                 (float)*(f16*)(lds + L_STLO + lb);
                *(f16*)(wsb + WS_RH + (size_t)brow * 2048 +
                        ((2 * kcol) ^ ((brow & 7) << 4))) = (f16)(sg * hv);
              }
            }
          } else if (t > 0) {  // o_{t-1} = tanh(h_t @ Ro + stashed base_o(t-1))
            const float pre = acc[q][e] + bsl[m * 16 + lcol];
            out[((size_t)brow * T_ + (t - 1)) * U_ + (cc_n - 2048)] = tanhf(pre);
          }
        }
      }
    }
    __syncthreads();
    // S5: stash base_o(t) for next step's o epilogue
    if (wid < 6 && is_o && t < T_) {
      float* bsl = (float*)(lds + L_BASE) + wid * 256;
      #pragma unroll
      for (int e = 0; e < 4; ++e) bsl[(kc * 4 + e) * 16 + lcol] = accb[e];
    }
    if (t == T_) break;

    // ---- barrier A; hide phase-2 base compute in the gap (waves 2,3) ----
    bar_arrive(cntA);
    if (wid == 2 || wid == 3) {
      const int r2 = wid - 2;
      const int bcol = 2048 + 16 * c + lcol;     // Rh-region original col
      const f16* kdp = kdT + (size_t)bcol * 128;
      const f16* ksp = ksT + (size_t)bcol * 128;
      const int arow = 16 * r2 + lcol;
      const int asw = (arow & 7) << 4;
      f32x4 a2 = {0, 0, 0, 0};
      #pragma unroll
      for (int j = 0; j < 8; ++j) {
        f16x8 a = *(f16x8*)(lds + L_SCR + arow * 512 + ((j * 64 + kc * 16) ^ asw));
        f16x8 b = (j < 4) ? *(const f16x8*)(kdp + j * 32 + kc * 8)
                          : *(const f16x8*)(ksp + (j - 4) * 32 + kc * 8);
        a2 = MFMA16(a, b, a2);
      }
      float* pb = (float*)(lds + L_P2B) + r2 * 256;
      #pragma unroll
      for (int e = 0; e < 4; ++e) {
        const int lrow = 16 * r2 + kc * 4 + e;
        const int crow = ((int*)(lds + L_CHC))[lrow];
        pb[(kc * 4 + e) * 16 + lcol] = a2[e] + kernel_c[(size_t)crow * 4096 + bcol] + bias[bcol];
      }
    }
    bar_wait(cntA, 256u * (unsigned)(t + 1));

    // ================= PHASE 2 =================
    // S0': stage rh
    {
      const char* sR = wsb + WS_RH + (size_t)row0 * 2048;
      #pragma unroll
      for (int it = 0; it < 8; ++it) {
        const int off = it * 8192 + tid * 16;
        *(f16x8*)(lds + L_STHI + off) = *(const f16x8*)(sR + off);
      }
    }
    __syncthreads();
    // S1': (r*h) @ Rh  (single f16 term; B streamed from L2-resident wT slice)
    f32x4 ach = {0, 0, 0, 0};
    {
      const f16* wp2 = wT + (size_t)(2048 + 16 * c + lcol) * 1024;
      const int lrow = 16 * rt + lcol;
      const int hb = lrow * 2048;
      const int hsw = (lrow & 7) << 4;
      #pragma unroll
      for (int j = 0; j < 8; ++j) {
        const int kt = kq * 8 + j;
        f16x8 a = *(f16x8*)(lds + L_STHI + hb + ((kt * 64 + kc * 16) ^ hsw));
        f16x8 b = *(const f16x8*)(wp2 + kt * 32 + kc * 8);
        ach = MFMA16(a, b, ach);
      }
    }
    __syncthreads();
    // S2': reduce k-quarters
    {
      float* ex = (float*)(lds + L_EXCH) + rt * 256;
      for (int rr = 1; rr <= 3; ++rr) {
        if (kq == rr) {
          #pragma unroll
          for (int e = 0; e < 4; ++e) ex[(kc * 4 + e) * 16 + lcol] = ach[e];
        }
        __syncthreads();
        if (kq == 0) {
          #pragma unroll
          for (int e = 0; e < 4; ++e) ach[e] += ex[(kc * 4 + e) * 16 + lcol];
        }
        __syncthreads();
      }
    }
    // S3': h update (waves 0,1); ch(t+1) prefetch (wave 7)
    if (wid < 2) {
      const float* pb = (float*)(lds + L_P2B) + rt * 256;
      #pragma unroll
      for (int e = 0; e < 4; ++e) {
        const int m = kc * 4 + e;
        const int brow = row0 + 16 * rt + m;
        const int ucol = 16 * c + lcol;
        const float hh = tanhf(ach[e] + pb[m * 16 + lcol]);
        const float z = ((float*)(wsb + WS_Z))[(size_t)brow * 1024 + ucol];
        const int gb = (2 * ucol) ^ ((brow & 7) << 4);
        f16* ph = (f16*)(wsb + WS_HHI + (size_t)brow * 2048 + gb);
        f16* pl = (f16*)(wsb + WS_HLO + (size_t)brow * 2048 + gb);
        const float hold = (float)*ph + (float)*pl;
        const float hnew = z * hold + (1.0f - z) * hh;
        const f16 nh = (f16)hnew;
        *ph = nh;
        *pl = (f16)(hnew - (float)nh);
      }
    }
    if (wid == 7 && lane < 32 && (t + 1) < T_)
      ((int*)(lds + L_CHC))[lane] = ch[(size_t)(row0 + lane) * T_ + (t + 1)];

    // ---- barrier B; hide _d/_s(t+1) compute in the gap ----
    bar_arrive(cntB);
    if (t + 1 < T_) compute_ds(t + 1, x, Wd, bd, Ws, bs, lds, row0, wid, lane);
    bar_wait(cntB, 256u * (unsigned)(t + 1));
  }
}

extern "C" void kernel_launch(void* const* d_in, const int* in_sizes, int n_in,
                              void* d_out, int out_size, void* d_ws, size_t ws_size,
                              hipStream_t stream) {
  const float* x    = (const float*)d_in[0];
  const int*   ch   = (const int*)d_in[1];
  const float* Wd   = (const float*)d_in[2];
  const float* bd_  = (const float*)d_in[3];
  const float* Ws   = (const float*)d_in[4];
  const float* bs_  = (const float*)d_in[5];
  const float* rk   = (const float*)d_in[6];
  const float* kc_  = (const float*)d_in[7];
  const float* kd   = (const float*)d_in[8];
  const float* ks   = (const float*)d_in[9];
  const float* bias = (const float*)d_in[10];
  char* wsb = (char*)d_ws;
  float* out = (float*)d_out;
  if (ws_size < (size_t)WS_END) return;

  // zero barriers + h planes (h_0 = 0)
  hipMemsetAsync(wsb, 0, WS_RH, stream);
  // transpose/convert weights to f16 frag-friendly layout
  prep_kernel<<<20480, 256, 0, stream>>>(rk, kd, ks,
      (f16*)(wsb + WS_WT), (f16*)(wsb + WS_KDT), (f16*)(wsb + WS_KST));
  // persistent recurrent kernel (160KB dynamic LDS -> 1 block/CU, 256 CUs)
  hipFuncSetAttribute((const void*)sgru_kernel,
                      hipFuncAttributeMaxDynamicSharedMemorySize, LDS_SZ);
  sgru_kernel<<<256, 512, LDS_SZ, stream>>>(x, ch, Wd, bd_, Ws, bs_, kc_, bias, wsb, out);
}

// Round 2
// 6299.967 us; speedup vs baseline: 3.8135x; 3.8135x over previous
//
#include <hip/hip_runtime.h>
#include <cstdint>
#include <cstddef>

typedef _Float16 f16;
typedef _Float16 f16x8 __attribute__((ext_vector_type(8)));
typedef float f32x4 __attribute__((ext_vector_type(4)));

#define T_  256
#define U_  1024

// ---- workspace offsets (bytes) ----
#define WS_FLA  0u                       // flagsA[256]
#define WS_FLB  1024u                    // flagsB[256]
#define WS_HHI  4096u                    // h hi plane: [128][1024] f16, col-swizzled
#define WS_HLO  (WS_HHI + 262144u)       // h lo plane
#define WS_RH   (WS_HLO + 262144u)       // rh plane: [128][1024] f16, swizzled
#define WS_WT   (WS_RH  + 262144u)       // recurrent_kernel^T f16 [4096][1024]
#define WS_KDT  (WS_WT  + 8388608u)      // kernel_d^T f16 [4096][128]
#define WS_KST  (WS_KDT + 1048576u)      // kernel_s^T f16 [4096][128]
#define WS_END  (WS_KST + 1048576u)

// ---- LDS offsets (bytes) ----  (block = 16 rows x {32 z | 32 r | 32 o} cols)
#define L_STHI 0         // staged h_hi (rh in phase2): [16][2048B]
#define L_STLO 32768     // staged h_lo
#define L_SCR  65536     // [_d|_s](t): [16 rows][256 f16] swizzled
#define L_BASE 73728     // base: [3q][2ch][256] f32 (o-slots persist a step)
#define L_EXCH 79872     // reduce exchange: [3kq][2ch][3q][256] f32
#define L_Z    98304     // z: [16][32] f32 (block-local!)
#define L_P2B  100352    // phase2 base: [2ch][256] f32
#define L_DST  102400    // d-state: [2 parity][16][2] f32
#define L_CHC  102656    // ch(t) cache: [16] int
#define LDS_SZ 102720

#define MFMA16(a,b,c) __builtin_amdgcn_mfma_f32_16x16x32_f16((a),(b),(c),0,0,0)

__device__ __forceinline__ float sigm(float v) { return 1.0f / (1.0f + __expf(-v)); }

// ---- coherent (L1/L2-bypass) memory ops: no cache-maintenance instructions ----
__device__ __forceinline__ void gload16(f16x8& d, const void* p) {
  asm volatile("global_load_dwordx4 %0, %1, off sc0 sc1" : "=&v"(d) : "v"(p));
}
__device__ __forceinline__ void gstore16(void* p, f16 v) {
  unsigned u = (unsigned)__builtin_bit_cast(unsigned short, v);
  asm volatile("global_store_short %0, %1, off sc0 sc1" :: "v"(p), "v"(u) : "memory");
}
__device__ __forceinline__ void vwait0() { asm volatile("s_waitcnt vmcnt(0)" ::: "memory"); }
__device__ __forceinline__ unsigned gload_flag(const unsigned* p) {
  unsigned v;
  asm volatile("global_load_dword %0, %1, off sc0 sc1\n\ts_waitcnt vmcnt(0)"
               : "=&v"(v) : "v"(p) : "memory");
  return v;
}
__device__ __forceinline__ void gstore_flag(unsigned* p, unsigned v) {
  asm volatile("global_store_dword %0, %1, off sc0 sc1" :: "v"(p), "v"(v) : "memory");
}

// ---- row-group barrier: per-block flags, relaxed bypass polling ----
__device__ __forceinline__ void bar_arrive(unsigned* flag, unsigned target, int tid) {
  __syncthreads();                       // all waves done (issuing waves vwait0'ed already)
  if (tid == 0) gstore_flag(flag, target);
}
__device__ __forceinline__ void bar_wait(unsigned* flags, int rg, unsigned target, int tid) {
  if (tid < 64) {
    const unsigned* f = flags + rg * 32 + (tid & 31);
    while (gload_flag(f) < target) __builtin_amdgcn_s_sleep(1);
  }
  __builtin_amdgcn_fence(__ATOMIC_ACQUIRE, "workgroup");
  __syncthreads();
}

// ---------- prep: transpose + f32->f16 convert weights ----------
__global__ __launch_bounds__(256) void prep_kernel(const float* __restrict__ rk,
                                                   const float* __restrict__ kd,
                                                   const float* __restrict__ ks,
                                                   f16* __restrict__ wT,
                                                   f16* __restrict__ kdT,
                                                   f16* __restrict__ ksT) {
  size_t i = (size_t)blockIdx.x * 256 + threadIdx.x;
  if (i < 4194304u) {                     // 1024*4096
    int k = (int)(i >> 12), n = (int)(i & 4095);
    wT[(size_t)n * 1024 + k] = (f16)rk[i];
  } else if (i < 4718592u) {              // + 128*4096
    size_t j = i - 4194304u;
    int k = (int)(j >> 12), n = (int)(j & 4095);
    kdT[(size_t)n * 128 + k] = (f16)kd[j];
  } else {
    size_t j = i - 4718592u;
    int k = (int)(j >> 12), n = (int)(j & 4095);
    ksT[(size_t)n * 128 + k] = (f16)ks[j];
  }
}

// ---------- _d(t), _s(t) into LDS scratch (waves 2..5) ----------
__device__ __forceinline__ void compute_ds(int t, const float* __restrict__ x,
                                           const float* __restrict__ Wd, const float* __restrict__ bd,
                                           const float* __restrict__ Ws, const float* __restrict__ bs,
                                           char* lds, int row0, int wid, int lane) {
  const int pOld = (t & 1) ^ 1, pNew = t & 1;
  float* dOld = (float*)(lds + L_DST) + pOld * 32;
  float* dNew = (float*)(lds + L_DST) + pNew * 32;
  if (wid == 2 || wid == 3) {
    const int j = (wid - 2) * 64 + lane;      // 0..127
    const float w0 = Wd[j], w1 = Wd[128 + j], b0 = bd[j];
    for (int r = 0; r < 16; ++r) {
      const size_t xb = ((size_t)(row0 + r) * T_ + t) * 5;
      float d0 = dOld[r * 2 + 0] + x[xb + 0];
      float d1 = dOld[r * 2 + 1] + x[xb + 1];
      if (wid == 2 && lane == r) { dNew[r * 2 + 0] = d0; dNew[r * 2 + 1] = d1; }
      float v = tanhf(d0 * w0 + d1 * w1 + b0);
      *(f16*)(lds + L_SCR + r * 512 + ((2 * j) ^ ((r & 7) << 4))) = (f16)v;
    }
  } else if (wid == 4 || wid == 5) {
    const int j = (wid - 4) * 64 + lane;
    const float w0 = Ws[j], w1 = Ws[128 + j], w2 = Ws[256 + j], b0 = bs[j];
    for (int r = 0; r < 16; ++r) {
      const size_t xb = ((size_t)(row0 + r) * T_ + t) * 5;
      float v = tanhf(x[xb + 2] * w0 + x[xb + 3] * w1 + x[xb + 4] * w2 + b0);
      *(f16*)(lds + L_SCR + r * 512 + ((2 * (128 + j)) ^ ((r & 7) << 4))) = (f16)v;
    }
  }
}

// ---------- persistent SGRU kernel: 256 blocks = 8 rg x 32 c ----------
__global__ __launch_bounds__(512, 2) void sgru_kernel(
    const float* __restrict__ x, const int* __restrict__ chp,
    const float* __restrict__ Wd, const float* __restrict__ bd,
    const float* __restrict__ Ws, const float* __restrict__ bs,
    const float* __restrict__ kcp, const float* __restrict__ bias,
    char* __restrict__ wsb, float* __restrict__ out) {
  extern __shared__ char lds[];
  const int tid  = threadIdx.x;
  const int wid  = tid >> 6;
  const int lane = tid & 63;
  const int lcol = lane & 15;
  const int kc   = lane >> 4;
  const int blk  = blockIdx.x;
  const int rg   = blk >> 5;        // row group 0..7 (16 rows)
  const int c    = blk & 31;        // col group 0..31 (32 cols per region)
  const int row0 = rg * 16;
  const int kq   = wid >> 1;        // k-quarter 0..3
  const int ch   = wid & 1;         // col-half 0..1

  const f16* __restrict__ wT  = (const f16*)(wsb + WS_WT);
  const f16* __restrict__ kdT = (const f16*)(wsb + WS_KDT);
  const f16* __restrict__ ksT = (const f16*)(wsb + WS_KST);
  unsigned* flagsA = (unsigned*)(wsb + WS_FLA);
  unsigned* flagsB = (unsigned*)(wsb + WS_FLB);

  // ---- init: d-state, ch(0), _d/_s(0), resident B fragments, own-h regs ----
  if (tid < 64) ((float*)(lds + L_DST))[tid] = 0.0f;
  if (tid < 16) ((int*)(lds + L_CHC))[tid] = chp[(size_t)(row0 + tid) * T_];
  __syncthreads();
  compute_ds(0, x, Wd, bd, Ws, bs, lds, row0, wid, lane);

  f16x8 Bp1[3][8];      // k-quarter of [Rzr|Ro] cols for this wave's 3 tiles
  #pragma unroll
  for (int q = 0; q < 3; ++q) {
    const int orig = (q == 2 ? 3072 : q * 1024) + 32 * c + 16 * ch + lcol;
    const f16* wp = wT + (size_t)orig * 1024;
    #pragma unroll
    for (int j = 0; j < 8; ++j)
      Bp1[q][j] = *(const f16x8*)(wp + (kq * 8 + j) * 32 + kc * 8);
  }
  float h_own[4] = {0.f, 0.f, 0.f, 0.f};   // waves 0,1: exact f32 h for own cols
  __syncthreads();

  for (int t = 0; ; ++t) {
    // ===== PHASE 1 =====
    // S0: issue h staging loads (bypass); overlap latency under S1
    f16x8 sh[4], sl[4];
    {
      const char* pH = wsb + WS_HHI + (size_t)row0 * 2048;
      const char* pL = wsb + WS_HLO + (size_t)row0 * 2048;
      #pragma unroll
      for (int it = 0; it < 4; ++it) {
        gload16(sh[it], pH + it * 8192 + tid * 16);
        gload16(sl[it], pL + it * 8192 + tid * 16);
      }
    }
    // S1: base(t) for 6 tiles (waves 0..5): [_d|_s] @ [kd;ks] + gather + bias
    f32x4 accb = {0.f, 0.f, 0.f, 0.f};
    if (wid < 6 && t < T_) {
      const int tq = wid >> 1, tch = wid & 1;
      const int bcol = (tq == 2 ? 3072 : tq * 1024) + 32 * c + 16 * tch + lcol;
      const f16* kdp = kdT + (size_t)bcol * 128;
      const f16* ksp = ksT + (size_t)bcol * 128;
      const int asw = (lcol & 7) << 4;
      #pragma unroll
      for (int j = 0; j < 8; ++j) {
        f16x8 a = *(f16x8*)(lds + L_SCR + lcol * 512 + ((j * 64 + kc * 16) ^ asw));
        f16x8 b = (j < 4) ? *(const f16x8*)(kdp + j * 32 + kc * 8)
                          : *(const f16x8*)(ksp + (j - 4) * 32 + kc * 8);
        accb = MFMA16(a, b, accb);
      }
      #pragma unroll
      for (int e = 0; e < 4; ++e) {
        const int crow = ((int*)(lds + L_CHC))[kc * 4 + e];
        accb[e] += kcp[(size_t)crow * 4096 + bcol] + bias[bcol];
      }
      if (tq < 2) {    // z,r bases park now; o base parks at S5
        float* bsl = (float*)(lds + L_BASE) + (tq * 2 + tch) * 256;
        #pragma unroll
        for (int e = 0; e < 4; ++e) bsl[(kc * 4 + e) * 16 + lcol] = accb[e];
      }
    }
    vwait0();
    {
      #pragma unroll
      for (int it = 0; it < 4; ++it) {
        *(f16x8*)(lds + L_STHI + it * 8192 + tid * 16) = sh[it];
        *(f16x8*)(lds + L_STLO + it * 8192 + tid * 16) = sl[it];
      }
    }
    __syncthreads();

    // S2: h_t @ [Rzr|Ro] (hi+lo terms), k-quarter per wave
    f32x4 acc[3] = {{0,0,0,0},{0,0,0,0},{0,0,0,0}};
    {
      const int hb = lcol * 2048;
      const int hsw = (lcol & 7) << 4;
      #pragma unroll
      for (int j = 0; j < 8; ++j) {
        const int kb = (((kq * 8 + j) * 64 + kc * 16) ^ hsw);
        f16x8 ahi = *(f16x8*)(lds + L_STHI + hb + kb);
        f16x8 alo = *(f16x8*)(lds + L_STLO + hb + kb);
        #pragma unroll
        for (int q = 0; q < 3; ++q) {
          acc[q] = MFMA16(ahi, Bp1[q][j], acc[q]);
          acc[q] = MFMA16(alo, Bp1[q][j], acc[q]);
        }
      }
    }
    // S3: single-round k-reduce into kq==0
    if (kq != 0) {
      float* ex = (float*)(lds + L_EXCH) + ((kq - 1) * 2 + ch) * 3 * 256;
      #pragma unroll
      for (int q = 0; q < 3; ++q)
        #pragma unroll
        for (int e = 0; e < 4; ++e)
          ex[q * 256 + (kc * 4 + e) * 16 + lcol] = acc[q][e];
    }
    __syncthreads();
    // S4: epilogue (waves 0,1): z->LDS, r->rh plane (bypass), o->out
    if (wid < 2) {
      const int ucol = 32 * c + 16 * ch + lcol;
      #pragma unroll
      for (int q = 0; q < 3; ++q) {
        const float* bsl = (float*)(lds + L_BASE) + (q * 2 + ch) * 256;
        #pragma unroll
        for (int e = 0; e < 4; ++e) {
          const int m = kc * 4 + e;
          float v = acc[q][e];
          #pragma unroll
          for (int kk = 0; kk < 3; ++kk)
            v += ((float*)(lds + L_EXCH))[((kk * 2 + ch) * 3 + q) * 256 + m * 16 + lcol];
          const int brow = row0 + m;
          if (q == 0) {
            if (t < T_) ((float*)(lds + L_Z))[m * 32 + 16 * ch + lcol] = sigm(v + bsl[m * 16 + lcol]);
          } else if (q == 1) {
            if (t < T_) {
              const float sg = sigm(v + bsl[m * 16 + lcol]);
              const int lb = m * 2048 + ((2 * ucol) ^ ((m & 7) << 4));
              const float hv = (float)*(f16*)(lds + L_STHI + lb) +
                               (float)*(f16*)(lds + L_STLO + lb);
              gstore16(wsb + WS_RH + (size_t)brow * 2048 + ((2 * ucol) ^ ((brow & 7) << 4)),
                       (f16)(sg * hv));
            }
          } else if (t > 0) {   // o_{t-1} = tanh(h_t @ Ro + base_o(t-1))
            out[((size_t)brow * T_ + (t - 1)) * U_ + ucol] = tanhf(v + bsl[m * 16 + lcol]);
          }
        }
      }
      vwait0();   // drain rh bypass stores (per-wave) before barrier flag
    }
    __syncthreads();
    // S5: stash base_o(t) for next step's o epilogue
    if (wid >= 4 && wid < 6 && t < T_) {
      float* bsl = (float*)(lds + L_BASE) + (4 + (wid & 1)) * 256;
      #pragma unroll
      for (int e = 0; e < 4; ++e) bsl[(kc * 4 + e) * 16 + lcol] = accb[e];
    }
    if (t == T_) break;

    // ---- barrier A (rh ready); hide phase2-base compute in the gap (waves 2,3) ----
    bar_arrive(flagsA + blk, (unsigned)(t + 1), tid);
    if (wid == 2 || wid == 3) {
      const int tch2 = wid - 2;
      const int bcol = 2048 + 32 * c + 16 * tch2 + lcol;
      const f16* kdp = kdT + (size_t)bcol * 128;
      const f16* ksp = ksT + (size_t)bcol * 128;
      const int asw = (lcol & 7) << 4;
      f32x4 a2 = {0.f, 0.f, 0.f, 0.f};
      #pragma unroll
      for (int j = 0; j < 8; ++j) {
        f16x8 a = *(f16x8*)(lds + L_SCR + lcol * 512 + ((j * 64 + kc * 16) ^ asw));
        f16x8 b = (j < 4) ? *(const f16x8*)(kdp + j * 32 + kc * 8)
                          : *(const f16x8*)(ksp + (j - 4) * 32 + kc * 8);
        a2 = MFMA16(a, b, a2);
      }
      float* pb = (float*)(lds + L_P2B) + tch2 * 256;
      #pragma unroll
      for (int e = 0; e < 4; ++e) {
        const int crow = ((int*)(lds + L_CHC))[kc * 4 + e];
        pb[(kc * 4 + e) * 16 + lcol] = a2[e] + kcp[(size_t)crow * 4096 + bcol] + bias[bcol];
      }
    }
    bar_wait(flagsA, rg, (unsigned)(t + 1), tid);

    // ===== PHASE 2 =====
    // S0': stage rh (bypass)
    {
      f16x8 sr[4];
      const char* pR = wsb + WS_RH + (size_t)row0 * 2048;
      #pragma unroll
      for (int it = 0; it < 4; ++it) gload16(sr[it], pR + it * 8192 + tid * 16);
      vwait0();
      #pragma unroll
      for (int it = 0; it < 4; ++it) *(f16x8*)(lds + L_STHI + it * 8192 + tid * 16) = sr[it];
    }
    __syncthreads();
    // S1': (r*h) @ Rh; B streamed from L2-resident wT slice
    f32x4 ach = {0.f, 0.f, 0.f, 0.f};
    {
      const f16* wp2 = wT + (size_t)(2048 + 32 * c + 16 * ch + lcol) * 1024;
      const int hb = lcol * 2048;
      const int hsw = (lcol & 7) << 4;
      #pragma unroll
      for (int j = 0; j < 8; ++j) {
        const int kt = kq * 8 + j;
        f16x8 a = *(f16x8*)(lds + L_STHI + hb + ((kt * 64 + kc * 16) ^ hsw));
        f16x8 b = *(const f16x8*)(wp2 + kt * 32 + kc * 8);
        ach = MFMA16(a, b, ach);
      }
    }
    // S2': single-round reduce
    if (kq != 0) {
      float* ex = (float*)(lds + L_EXCH) + ((kq - 1) * 2 + ch) * 3 * 256;
      #pragma unroll
      for (int e = 0; e < 4; ++e) ex[(kc * 4 + e) * 16 + lcol] = ach[e];
    }
    __syncthreads();
    // S3': h update (waves 0,1), h kept exact in regs; planes written bypass
    if (wid < 2) {
      const int ucol = 32 * c + 16 * ch + lcol;
      const float* pb = (float*)(lds + L_P2B) + ch * 256;
      #pragma unroll
      for (int e = 0; e < 4; ++e) {
        const int m = kc * 4 + e;
        float v = ach[e];
        #pragma unroll
        for (int kk = 0; kk < 3; ++kk)
          v += ((float*)(lds + L_EXCH))[((kk * 2 + ch) * 3) * 256 + m * 16 + lcol];
        const int brow = row0 + m;
        const float hh = tanhf(v + pb[m * 16 + lcol]);
        const float z = ((float*)(lds + L_Z))[m * 32 + 16 * ch + lcol];
        const float hnew = z * h_own[e] + (1.0f - z) * hh;
        h_own[e] = hnew;
        const f16 nh = (f16)hnew;
        const f16 nl = (f16)(hnew - (float)nh);
        const int gb = (2 * ucol) ^ ((brow & 7) << 4);
        gstore16(wsb + WS_HHI + (size_t)brow * 2048 + gb, nh);
        gstore16(wsb + WS_HLO + (size_t)brow * 2048 + gb, nl);
      }
      vwait0();   // drain h bypass stores before barrier flag
    }
    if (wid == 7 && lane < 16 && (t + 1) < T_)
      ((int*)(lds + L_CHC))[lane] = chp[(size_t)(row0 + lane) * T_ + (t + 1)];

    // ---- barrier B (h ready); hide _d/_s(t+1) compute in the gap ----
    bar_arrive(flagsB + blk, (unsigned)(t + 1), tid);
    if (t + 1 < T_) compute_ds(t + 1, x, Wd, bd, Ws, bs, lds, row0, wid, lane);
    bar_wait(flagsB, rg, (unsigned)(t + 1), tid);
  }
}

extern "C" void kernel_launch(void* const* d_in, const int* in_sizes, int n_in,
                              void* d_out, int out_size, void* d_ws, size_t ws_size,
                              hipStream_t stream) {
  const float* x    = (const float*)d_in[0];
  const int*   ch   = (const int*)d_in[1];
  const float* Wd   = (const float*)d_in[2];
  const float* bd_  = (const float*)d_in[3];
  const float* Ws   = (const float*)d_in[4];
  const float* bs_  = (const float*)d_in[5];
  const float* rk   = (const float*)d_in[6];
  const float* kc_  = (const float*)d_in[7];
  const float* kd   = (const float*)d_in[8];
  const float* ks   = (const float*)d_in[9];
  const float* bias = (const float*)d_in[10];
  char* wsb = (char*)d_ws;
  float* out = (float*)d_out;
  if (ws_size < (size_t)WS_END) return;

  // zero flags + h planes (h_0 = 0)
  hipMemsetAsync(wsb, 0, WS_RH, stream);
  // transpose/convert weights to f16 frag layout
  prep_kernel<<<20480, 256, 0, stream>>>(rk, kd, ks,
      (f16*)(wsb + WS_WT), (f16*)(wsb + WS_KDT), (f16*)(wsb + WS_KST));
  // persistent recurrent kernel (1 block/CU via LDS, 256 CUs)
  hipFuncSetAttribute((const void*)sgru_kernel,
                      hipFuncAttributeMaxDynamicSharedMemorySize, LDS_SZ);
  sgru_kernel<<<256, 512, LDS_SZ, stream>>>(x, ch, Wd, bd_, Ws, bs_, kc_, bias, wsb, out);
}

// Round 3
// 2822.880 us; speedup vs baseline: 8.5109x; 2.2318x over previous
//
#include <hip/hip_runtime.h>
#include <cstdint>
#include <cstddef>

typedef _Float16 f16;
typedef _Float16 f16x8 __attribute__((ext_vector_type(8)));
typedef float f32x4 __attribute__((ext_vector_type(4)));

#define T_  256
#define U_  1024

// ---- workspace offsets (bytes) ----
#define WS_FLA  0u
#define WS_FLB  1024u
#define WS_HHI  4096u                    // h hi plane [128][1024] f16, col-swizzled
#define WS_HLO  (WS_HHI + 262144u)
#define WS_RH   (WS_HLO + 262144u)       // rh plane
#define WS_WT   (WS_RH  + 262144u)       // recurrent_kernel^T f16 [4096][1024]
#define WS_KDT  (WS_WT  + 8388608u)      // kernel_d^T f16 [4096][128]
#define WS_KST  (WS_KDT + 1048576u)      // kernel_s^T f16 [4096][128]
#define WS_A    (WS_KST + 1048576u)      // A=[tanh(dWd)|tanh(sWs)] [128][256][256] f16
#define WS_END  (WS_A   + 16777216u)

// ---- LDS ----
#define L_STHI 0         // staged h_hi (rh in ph2): [16][2048B]
#define L_STLO 32768
#define L_ABUF 65536     // A(t+1) slice [16][512B] swizzled
#define L_EXCH 73728     // 24 tiles x 1040B
#define L_Z    98688     // [16][32] f32
#define L_LB   100736    // base dbuf: 2 x [16 rows][4 reg][32] f32
#define LDS_SZ 117120
#define EXT(kq,ch,q) (L_EXCH + (((kq)*2+(ch))*3+(q))*1040)

#define MFMA16(a,b,c) __builtin_amdgcn_mfma_f32_16x16x32_f16((a),(b),(c),0,0,0)
__device__ __forceinline__ float sigm(float v) { return 1.0f / (1.0f + __expf(-v)); }

// ---- L2-bypass coherent ops ----
__device__ __forceinline__ void gload16(f16x8& d, const void* p) {
  asm volatile("global_load_dwordx4 %0, %1, off sc0 sc1" : "=&v"(d) : "v"(p));
}
__device__ __forceinline__ void gstore16(void* p, f16 v) {
  unsigned u = (unsigned)__builtin_bit_cast(unsigned short, v);
  asm volatile("global_store_short %0, %1, off sc0 sc1" :: "v"(p), "v"(u) : "memory");
}
__device__ __forceinline__ void vwait0() { asm volatile("s_waitcnt vmcnt(0)" ::: "memory"); }
__device__ __forceinline__ unsigned gload_flag(const unsigned* p) {
  unsigned v;
  asm volatile("global_load_dword %0, %1, off sc0 sc1\n\ts_waitcnt vmcnt(0)"
               : "=&v"(v) : "v"(p) : "memory");
  return v;
}
__device__ __forceinline__ void gstore_flag(unsigned* p, unsigned v) {
  asm volatile("global_store_dword %0, %1, off sc0 sc1" :: "v"(p), "v"(v) : "memory");
}
__device__ __forceinline__ void bar_wait(unsigned* flags, int rg, unsigned target, int tid) {
  if (tid < 64) {
    const unsigned* f = flags + rg * 32 + (tid & 31);
    while (gload_flag(f) < target) __builtin_amdgcn_s_sleep(1);
  }
  __builtin_amdgcn_fence(__ATOMIC_ACQUIRE, "workgroup");
  __syncthreads();
}

// ---------- prep: weight transposes ----------
__global__ __launch_bounds__(256) void prep_kernel(const float* __restrict__ rk,
                                                   const float* __restrict__ kd,
                                                   const float* __restrict__ ks,
                                                   f16* __restrict__ wT,
                                                   f16* __restrict__ kdT,
                                                   f16* __restrict__ ksT) {
  size_t i = (size_t)blockIdx.x * 256 + threadIdx.x;
  if (i < 4194304u) {
    int k = (int)(i >> 12), n = (int)(i & 4095);
    wT[(size_t)n * 1024 + k] = (f16)rk[i];
  } else if (i < 4718592u) {
    size_t j = i - 4194304u;
    int k = (int)(j >> 12), n = (int)(j & 4095);
    kdT[(size_t)n * 128 + k] = (f16)kd[j];
  } else {
    size_t j = i - 4718592u;
    int k = (int)(j >> 12), n = (int)(j & 4095);
    ksT[(size_t)n * 128 + k] = (f16)ks[j];
  }
}

// ---------- prep: A = [tanh(d@Wd+bd) | tanh(s@Ws+bs)], d = cumsum ----------
__global__ __launch_bounds__(64) void acum_kernel(const float* __restrict__ x,
    const float* __restrict__ Wd, const float* __restrict__ bd,
    const float* __restrict__ Ws, const float* __restrict__ bs,
    f16* __restrict__ A) {
  const int b = blockIdx.x, lane = threadIdx.x;
  float w0[4], w1[4], w2[4], bb[4];
  #pragma unroll
  for (int q = 0; q < 4; ++q) {
    int col = lane + 64 * q;
    if (col < 128) { w0[q] = Wd[col]; w1[q] = Wd[128 + col]; w2[q] = 0.f; bb[q] = bd[col]; }
    else { int c2 = col - 128; w0[q] = Ws[c2]; w1[q] = Ws[128 + c2]; w2[q] = Ws[256 + c2]; bb[q] = bs[c2]; }
  }
  float d0 = 0.f, d1 = 0.f;
  for (int t = 0; t < T_; ++t) {
    const float* xp = x + ((size_t)b * T_ + t) * 5;
    float x0 = xp[0], x1 = xp[1], x2 = xp[2], x3 = xp[3], x4 = xp[4];
    d0 += x0; d1 += x1;
    f16* Ap = A + ((size_t)b * T_ + t) * 256;
    #pragma unroll
    for (int q = 0; q < 4; ++q) {
      int col = lane + 64 * q;
      float v = (col < 128) ? tanhf(d0 * w0[q] + d1 * w1[q] + bb[q])
                            : tanhf(x2 * w0[q] + x3 * w1[q] + x4 * w2[q] + bb[q]);
      Ap[col] = (f16)v;
    }
  }
}

// ---------- persistent SGRU: 256 blocks = 8 rg x 32 c ----------
__global__ __launch_bounds__(512) void sgru_kernel(
    const int* __restrict__ chp, const float* __restrict__ kcp,
    const float* __restrict__ bias, char* __restrict__ wsb,
    float* __restrict__ out) {
  extern __shared__ char lds[];
  const int tid  = threadIdx.x;
  const int wid  = tid >> 6;
  const int lane = tid & 63;
  const int lcol = lane & 15;
  const int kc   = lane >> 4;
  const int blk  = blockIdx.x;
  const int rg   = blk >> 5;
  const int c    = blk & 31;
  const int row0 = rg * 16;
  const int kq   = wid >> 1;
  const int chh  = wid & 1;
  // reduce-thread mapping: 512 threads -> (rch, rm, rl)
  const int rp = tid & 255, rm = rp >> 4, rl = rp & 15, rch = tid >> 8;
  const int rucol = 32 * c + 16 * rch + rl;
  // this wave's base tile
  const int wreg = wid >> 1, wch = wid & 1;
  const int bcolw = wreg * 1024 + 32 * c + 16 * wch + lcol;

  const f16* __restrict__ wT  = (const f16*)(wsb + WS_WT);
  const f16* __restrict__ kdT = (const f16*)(wsb + WS_KDT);
  const f16* __restrict__ ksT = (const f16*)(wsb + WS_KST);
  const f16* __restrict__ Ap  = (const f16*)(wsb + WS_A);
  unsigned* flagsA = (unsigned*)(wsb + WS_FLA);
  unsigned* flagsB = (unsigned*)(wsb + WS_FLB);

  // ---- init: resident fragments ----
  f16x8 Bp1[3][8], BpB[8];
  #pragma unroll
  for (int q = 0; q < 3; ++q) {
    const int orig = (q == 2 ? 3072 : q * 1024) + 32 * c + 16 * chh + lcol;
    const f16* wp = wT + (size_t)orig * 1024;
    #pragma unroll
    for (int j = 0; j < 8; ++j)
      Bp1[q][j] = *(const f16x8*)(wp + (kq * 8 + j) * 32 + kc * 8);
  }
  #pragma unroll
  for (int j = 0; j < 8; ++j)
    BpB[j] = (j < 4) ? *(const f16x8*)(kdT + (size_t)bcolw * 128 + j * 32 + kc * 8)
                     : *(const f16x8*)(ksT + (size_t)bcolw * 128 + (j - 4) * 32 + kc * 8);
  const float biasv = bias[bcolw];
  float h_own = 0.f;
  int chreg[4]; float kcv[4];

  // stage A(0) + kc(0) gathers + chreg = ch(1)
  {
    f16x8 av = *(const f16x8*)(Ap + ((size_t)(row0 + (tid >> 5)) * T_ + 0) * 256 + (tid & 31) * 8);
    *(f16x8*)(lds + L_ABUF + (tid >> 5) * 512 + (((tid & 31) * 16) ^ (((tid >> 5) & 7) << 4))) = av;
  }
  #pragma unroll
  for (int e = 0; e < 4; ++e) {
    const size_t r = (size_t)(row0 + kc * 4 + e) * T_;
    kcv[e] = kcp[(size_t)chp[r] * 4096 + bcolw];
    chreg[e] = chp[r + 1];
  }
  __syncthreads();
  // base(0) -> LB[0]
  {
    f32x4 ab = {0.f, 0.f, 0.f, 0.f};
    #pragma unroll
    for (int j = 0; j < 8; ++j) {
      f16x8 a = *(f16x8*)(lds + L_ABUF + lcol * 512 + ((j * 64 + kc * 16) ^ ((lcol & 7) << 4)));
      ab = MFMA16(a, BpB[j], ab);
    }
    float* lb0 = (float*)(lds + L_LB);
    #pragma unroll
    for (int e = 0; e < 4; ++e)
      lb0[((kc * 4 + e) * 4 + wreg) * 32 + 16 * wch + lcol] = ab[e] + kcv[e] + biasv;
  }
  __syncthreads();

  for (int t = 0; ; ++t) {
    const int p = t & 1;
    float* LBp = (float*)(lds + L_LB + p * 8192);
    float* LBq = (float*)(lds + L_LB + (p ^ 1) * 8192);
    // ===== PHASE 1 =====
    f16x8 sh[4], sl[4];
    {
      const char* pH = wsb + WS_HHI + (size_t)row0 * 2048;
      const char* pL = wsb + WS_HLO + (size_t)row0 * 2048;
      #pragma unroll
      for (int it = 0; it < 4; ++it) {
        gload16(sh[it], pH + it * 8192 + tid * 16);
        gload16(sl[it], pL + it * 8192 + tid * 16);
      }
    }
    vwait0();
    #pragma unroll
    for (int it = 0; it < 4; ++it) {
      *(f16x8*)(lds + L_STHI + it * 8192 + tid * 16) = sh[it];
      *(f16x8*)(lds + L_STLO + it * 8192 + tid * 16) = sl[it];
    }
    // issue next-step A slice, kc(t+1) gathers (from chreg), ch(t+2)
    const bool havA = (t + 1 < T_);
    f16x8 av;
    if (havA) {
      av = *(const f16x8*)(Ap + ((size_t)(row0 + (tid >> 5)) * T_ + (t + 1)) * 256 + (tid & 31) * 8);
      #pragma unroll
      for (int e = 0; e < 4; ++e) kcv[e] = kcp[(size_t)chreg[e] * 4096 + bcolw];
      if (t + 2 < T_) {
        #pragma unroll
        for (int e = 0; e < 4; ++e)
          chreg[e] = chp[(size_t)(row0 + kc * 4 + e) * T_ + (t + 2)];
      }
    }
    __syncthreads();
    // main MFMA: h @ [Rzr|Ro] (hi+lo)
    f32x4 acc[3] = {{0,0,0,0},{0,0,0,0},{0,0,0,0}};
    {
      const int hb = lcol * 2048, hsw = (lcol & 7) << 4;
      #pragma unroll
      for (int j = 0; j < 8; ++j) {
        const int kb = (((kq * 8 + j) * 64 + kc * 16) ^ hsw);
        f16x8 ahi = *(f16x8*)(lds + L_STHI + hb + kb);
        f16x8 alo = *(f16x8*)(lds + L_STLO + hb + kb);
        #pragma unroll
        for (int q = 0; q < 3; ++q) {
          acc[q] = MFMA16(ahi, Bp1[q][j], acc[q]);
          acc[q] = MFMA16(alo, Bp1[q][j], acc[q]);
        }
      }
    }
    // dump exchange + write A(t+1) into ABUF
    #pragma unroll
    for (int q = 0; q < 3; ++q)
      #pragma unroll
      for (int e = 0; e < 4; ++e)
        *(float*)(lds + EXT(kq, chh, q) + e * 260 + (kc * 16 + lcol) * 4) = acc[q][e];
    if (havA)
      *(f16x8*)(lds + L_ABUF + (tid >> 5) * 512 + (((tid & 31) * 16) ^ (((tid >> 5) & 7) << 4))) = av;
    __syncthreads();
    // reduce + epilogue: every thread handles (rch, rm, rl) for q=0,1,2
    float vz = 0.f, vr = 0.f, vo = 0.f;
    {
      const int off = (rm & 3) * 260 + ((rm >> 2) * 16 + rl) * 4;
      #pragma unroll
      for (int k2 = 0; k2 < 4; ++k2) {
        vz += *(float*)(lds + EXT(k2, rch, 0) + off);
        vr += *(float*)(lds + EXT(k2, rch, 1) + off);
        vo += *(float*)(lds + EXT(k2, rch, 2) + off);
      }
    }
    float opre = 0.f;
    if (t > 0) opre = tanhf(vo + LBq[(rm * 4 + 3) * 32 + 16 * rch + rl]);
    if (t < T_) {
      ((float*)(lds + L_Z))[rm * 32 + 16 * rch + rl] =
          sigm(vz + LBp[(rm * 4 + 0) * 32 + 16 * rch + rl]);
      const float rv = sigm(vr + LBp[(rm * 4 + 1) * 32 + 16 * rch + rl]);
      const int lb = rm * 2048 + ((2 * rucol) ^ ((rm & 7) << 4));
      const float hv = (float)*(f16*)(lds + L_STHI + lb) + (float)*(f16*)(lds + L_STLO + lb);
      gstore16(wsb + WS_RH + (size_t)(row0 + rm) * 2048 + ((2 * rucol) ^ (((row0 + rm) & 7) << 4)),
               (f16)(rv * hv));
    }
    if (t == T_) {
      out[((size_t)(row0 + rm) * T_ + (t - 1)) * U_ + rucol] = opre;
      break;
    }
    vwait0();          // drain rh bypass stores
    __syncthreads();
    if (tid == 0) gstore_flag(flagsA + blk, (unsigned)(t + 1));
    // GAP-A: base(t+1) MFMA + o(t-1) store
    if (havA) {
      f32x4 ab = {0.f, 0.f, 0.f, 0.f};
      #pragma unroll
      for (int j = 0; j < 8; ++j) {
        f16x8 a = *(f16x8*)(lds + L_ABUF + lcol * 512 + ((j * 64 + kc * 16) ^ ((lcol & 7) << 4)));
        ab = MFMA16(a, BpB[j], ab);
      }
      #pragma unroll
      for (int e = 0; e < 4; ++e)
        LBq[((kc * 4 + e) * 4 + wreg) * 32 + 16 * wch + lcol] = ab[e] + kcv[e] + biasv;
    }
    if (t > 0) out[((size_t)(row0 + rm) * T_ + (t - 1)) * U_ + rucol] = opre;
    bar_wait(flagsA, rg, (unsigned)(t + 1), tid);

    // ===== PHASE 2 =====
    f16x8 sr[4], b2[8];
    {
      const char* pR = wsb + WS_RH + (size_t)row0 * 2048;
      #pragma unroll
      for (int it = 0; it < 4; ++it) gload16(sr[it], pR + it * 8192 + tid * 16);
      const f16* wp2 = wT + (size_t)(2048 + 32 * c + 16 * chh + lcol) * 1024;
      #pragma unroll
      for (int j = 0; j < 8; ++j) b2[j] = *(const f16x8*)(wp2 + (kq * 8 + j) * 32 + kc * 8);
    }
    vwait0();
    #pragma unroll
    for (int it = 0; it < 4; ++it)
      *(f16x8*)(lds + L_STHI + it * 8192 + tid * 16) = sr[it];
    __syncthreads();
    f32x4 a2 = {0.f, 0.f, 0.f, 0.f};
    {
      const int hb = lcol * 2048, hsw = (lcol & 7) << 4;
      #pragma unroll
      for (int j = 0; j < 8; ++j) {
        f16x8 a = *(f16x8*)(lds + L_STHI + hb + (((kq * 8 + j) * 64 + kc * 16) ^ hsw));
        a2 = MFMA16(a, b2[j], a2);
      }
    }
    #pragma unroll
    for (int e = 0; e < 4; ++e)
      *(float*)(lds + EXT(kq, chh, 0) + e * 260 + (kc * 16 + lcol) * 4) = a2[e];
    __syncthreads();
    // h update: 1 elem/thread
    {
      const int off = (rm & 3) * 260 + ((rm >> 2) * 16 + rl) * 4;
      float v = 0.f;
      #pragma unroll
      for (int k2 = 0; k2 < 4; ++k2) v += *(float*)(lds + EXT(k2, rch, 0) + off);
      const float hh = tanhf(v + LBp[(rm * 4 + 2) * 32 + 16 * rch + rl]);
      const float zv = ((float*)(lds + L_Z))[rm * 32 + 16 * rch + rl];
      h_own = zv * h_own + (1.f - zv) * hh;
      const f16 nh = (f16)h_own;
      const f16 nl = (f16)(h_own - (float)nh);
      const int gb = (2 * rucol) ^ (((row0 + rm) & 7) << 4);
      gstore16(wsb + WS_HHI + (size_t)(row0 + rm) * 2048 + gb, nh);
      gstore16(wsb + WS_HLO + (size_t)(row0 + rm) * 2048 + gb, nl);
    }
    vwait0();          // drain h bypass stores
    __syncthreads();
    if (tid == 0) gstore_flag(flagsB + blk, (unsigned)(t + 1));
    bar_wait(flagsB, rg, (unsigned)(t + 1), tid);
  }
}

extern "C" void kernel_launch(void* const* d_in, const int* in_sizes, int n_in,
                              void* d_out, int out_size, void* d_ws, size_t ws_size,
                              hipStream_t stream) {
  const float* x    = (const float*)d_in[0];
  const int*   ch   = (const int*)d_in[1];
  const float* Wd   = (const float*)d_in[2];
  const float* bd_  = (const float*)d_in[3];
  const float* Ws   = (const float*)d_in[4];
  const float* bs_  = (const float*)d_in[5];
  const float* rk   = (const float*)d_in[6];
  const float* kc_  = (const float*)d_in[7];
  const float* kd   = (const float*)d_in[8];
  const float* ks   = (const float*)d_in[9];
  const float* bias = (const float*)d_in[10];
  char* wsb = (char*)d_ws;
  float* out = (float*)d_out;
  if (ws_size < (size_t)WS_END) return;

  // zero flags + h planes
  hipMemsetAsync(wsb, 0, WS_RH, stream);
  prep_kernel<<<20480, 256, 0, stream>>>(rk, kd, ks,
      (f16*)(wsb + WS_WT), (f16*)(wsb + WS_KDT), (f16*)(wsb + WS_KST));
  acum_kernel<<<128, 64, 0, stream>>>(x, Wd, bd_, Ws, bs_, (f16*)(wsb + WS_A));
  hipFuncSetAttribute((const void*)sgru_kernel,
                      hipFuncAttributeMaxDynamicSharedMemorySize, LDS_SZ);
  sgru_kernel<<<256, 512, LDS_SZ, stream>>>(ch, kc_, bias, wsb, out);
}